// Round 6
// baseline (2380.167 us; speedup 1.0000x reference)
//
#include <hip/hip_runtime.h>
#include <stdint.h>

// Problem constants
constexpr int BB = 64;     // batch
constexpr int SS = 512;    // seq len
constexpr int DD = 256;    // emb dim
constexpr int HH = 256;    // hidden
constexpr int NHH = 4;     // heads
constexpr int KK = 1024;   // NH*H recurrent input dim

// ROUNDS 2-5 LESSON: the allocator budgets registers for 2 WGs/CU no matter
// what attributes say: 512-thr WG -> 128 VGPRs, 1024-thr -> 64. Exceeding it
// => loads sunk into the loop (L2 restream) or scratch spills (r5: 15.7 GB
// HBM writes). Single-CU residency tops out ~200/512 KB -> >=1.2us/step.
//
// ROUND 6 DESIGN: 4 WGs per batch element (256 WGs = 256 CUs), K-split in
// quarters. hcat chunk q IS head q's state -> WG q updates h_q locally.
// Weights per WG = 128 KB = 16 uint4/thread (64 regs: fits the 128 cap with
// room). Only cross-WG traffic: 1 KB partial sums per WG per step, exchanged
// via parity-double-buffered global region + monotone per-WG flags
// (release/acquire, agent scope). Parity is race-free: seeing flag >= s+2
// proves the peer finished reading step-s partials.
constexpr int TT = 512;

typedef _Float16 f16;
typedef _Float16 f16x2 __attribute__((ext_vector_type(2)));

__device__ inline float dot2p(uint32_t a, uint32_t b, float c) {
  f16x2 av = __builtin_bit_cast(f16x2, a);
  f16x2 bv = __builtin_bit_cast(f16x2, b);
#if defined(__has_builtin)
#if __has_builtin(__builtin_amdgcn_fdot2)
  return __builtin_amdgcn_fdot2(av, bv, c, false);
#else
  return c + (float)av.x * (float)bv.x + (float)av.y * (float)bv.y;
#endif
#else
  return c + (float)av.x * (float)bv.x + (float)av.y * (float)bv.y;
#endif
}

__device__ inline float dot8(uint4 w, uint4 a, float c) {
  c = dot2p(w.x, a.x, c);
  c = dot2p(w.y, a.y, c);
  c = dot2p(w.z, a.z, c);
  c = dot2p(w.w, a.w, c);
  return c;
}

__device__ inline uint32_t pack2(float a, float b) {
  f16x2 v;
  v.x = (f16)a;
  v.y = (f16)b;
  return __builtin_bit_cast(uint32_t, v);
}

__device__ inline float fast_tanh(float x) {
  x = fminf(fmaxf(x, -15.f), 15.f);
  float e = __expf(2.f * x);
  return 1.f - 2.f / (e + 1.f);
}

// ---------------------------------------------------------------------------
// Prep A1: pack Wh [256,1024] fp32 -> Wpack f16.
// Wpack[(q*16 + m)*512 + t]: t = half*256 + o; holds
// Wh[o][256q + 128*half + 8m .. +8) as 8 packed f16. Coalesced in t.
// ---------------------------------------------------------------------------
__global__ void k_pack_wh(const float* __restrict__ Wh, uint4* __restrict__ Wpack) {
  int gid = blockIdx.x * blockDim.x + threadIdx.x;  // 32768
  int q = gid >> 13;
  int m = (gid >> 9) & 15;
  int t = gid & 511;
  int o = t & 255, half = t >> 8;
  int row = o;
  int col = 256 * q + 128 * half + 8 * m;
  const float* s = Wh + row * KK + col;
  uint4 w;
  w.x = pack2(s[0], s[1]);
  w.y = pack2(s[2], s[3]);
  w.z = pack2(s[4], s[5]);
  w.w = pack2(s[6], s[7]);
  Wpack[gid] = w;
}

// ---------------------------------------------------------------------------
// Prep A2/A3: transpose src[r, C] (r in [0,256)) -> dst[c*256 + r]
// ---------------------------------------------------------------------------
__global__ void k_transpose8(const float* __restrict__ src, float* __restrict__ dst,
                             int C, int total) {
  int gid = blockIdx.x * blockDim.x + threadIdx.x;
  if (gid >= total) return;
  int r = gid & 255, c = gid >> 8;
  dst[gid] = src[r * C + c];
}

// ---------------------------------------------------------------------------
// Prep B: U[row, o] = emb[src[row]] @ Wi^T + bi + bh   (f16 out)
// ---------------------------------------------------------------------------
__global__ __launch_bounds__(256) void k_precompute_u(
    const int* __restrict__ src, const float* __restrict__ emb,
    const float* __restrict__ WiT, const float* __restrict__ bi,
    const float* __restrict__ bh, f16* __restrict__ U) {
  __shared__ float xs[32 * 256];
  __shared__ int srcs[32];
  const int tid = threadIdx.x;
  const int row0 = blockIdx.x * 32;
  if (tid < 32) srcs[tid] = src[row0 + tid];
  __syncthreads();
  for (int i = tid; i < 32 * 256; i += 256) {
    int r = i >> 8, d = i & 255;
    xs[i] = emb[srcs[r] * DD + d];
  }
  __syncthreads();
  const int o = tid;
  float acc[32];
#pragma unroll
  for (int r = 0; r < 32; ++r) acc[r] = 0.f;
  for (int d0 = 0; d0 < 256; d0 += 8) {
    float w[8];
#pragma unroll
    for (int j = 0; j < 8; ++j) w[j] = WiT[(d0 + j) * 256 + o];  // coalesced
#pragma unroll
    for (int r = 0; r < 32; ++r) {
      const float4* xp = (const float4*)(xs + r * 256 + d0);  // broadcast
      float4 x0 = xp[0], x1 = xp[1];
      acc[r] += x0.x * w[0] + x0.y * w[1] + x0.z * w[2] + x0.w * w[3] +
                x1.x * w[4] + x1.y * w[5] + x1.z * w[6] + x1.w * w[7];
    }
  }
  float bias = bi[o] + bh[o];
#pragma unroll
  for (int r = 0; r < 32; ++r)
    U[(size_t)(row0 + r) * HH + o] = (f16)(acc[r] + bias);
}

// ---------------------------------------------------------------------------
// Init: zero the flag array (ws is poisoned to 0xAA before every launch).
// ---------------------------------------------------------------------------
__global__ void k_init_flags(int* __restrict__ Flg) {
  Flg[threadIdx.x] = 0;
}

// ---------------------------------------------------------------------------
// Main recurrence: 4 WGs (512 thr) per batch element; blockIdx = q*64 + b so
// a batch's 4 WGs share idx%8 (same-XCD heuristic under round-robin mapping;
// correctness does not depend on it -- agent-scope release/acquire).
// Thread t: o = t&255 (output), half = t>>8 (which 128 of the 256-input
// chunk). 16 resident uint4 weights/thread = the whole K-quarter on-CU.
// ---------------------------------------------------------------------------
__global__ void __attribute__((amdgpu_flat_work_group_size(512, 512)))
k_recurrence(
    const uint4* __restrict__ Wpack, const f16* __restrict__ U,
    const float* __restrict__ fix_src, const int* __restrict__ input_len,
    const float* __restrict__ fc1T, const float* __restrict__ fc1_b,
    const float* __restrict__ fc2_W, const float* __restrict__ fc2_b,
    float* __restrict__ out, float* __restrict__ Pg, float* __restrict__ FPg,
    int* __restrict__ Flg) {
  __shared__ float part[512];   // 2 KB
  __shared__ uint4 achunk[32];  // 512 B: own hcat chunk (= own head) as f16
  __shared__ float hloc[256];   // 1 KB: fp32 master h for own head
  __shared__ float hidb[256];   // 1 KB (epilogue, WG0 only)
  f16* ach_h = (f16*)achunk;

  const int idx = blockIdx.x;
  const int b = idx & 63;
  const int q = idx >> 6;
  const int t = threadIdx.x;
  const int o = t & 255;
  const int half = t >> 8;

  // one-time: this quarter's weights into VGPRs (64 regs; fits the cap)
  uint4 w[16];
  const uint4* wp = Wpack + (q * 16) * TT + t;
#pragma unroll
  for (int m = 0; m < 16; ++m) w[m] = wp[m * TT];
#pragma unroll
  for (int m = 0; m < 16; ++m)
    asm volatile("" : "+v"(w[m].x), "+v"(w[m].y), "+v"(w[m].z), "+v"(w[m].w));

  if (t < 256) hloc[t] = 0.f;
  if (t < 32) achunk[t] = make_uint4(0u, 0u, 0u, 0u);
  __syncthreads();

  const int len = input_len[b];
  const f16* Ub = U + (size_t)b * SS * HH;
  const float* fsb = fix_src + b * SS;
  int* flb = Flg + b * 4;  // this batch's 4 flags (monotone step counters)
  // Pg layout: [parity][b][q][o] -> parity*65536 + b*1024 + q*256 + o

#pragma unroll 1
  for (int s = 0; s < len; ++s) {
    float uval = 0.f, dval = 0.f;
    if (t < 256) {
      uval = (float)Ub[s * HH + o];
      dval = fsb[s];
    }
    float acc = 0.f;
    const uint4* ap = achunk + half * 16;  // wave-uniform -> broadcast
#pragma unroll
    for (int m = 0; m < 16; ++m) acc = dot8(w[m], ap[m], acc);
    part[t] = acc;
    __syncthreads();
    const int par = s & 1;
    float pown = 0.f;
    if (t < 256) {
      pown = part[o] + part[256 + o];
      Pg[par * 65536 + b * 1024 + q * 256 + o] = pown;  // 1 KB coalesced
    }
    __syncthreads();  // barrier's vmcnt(0) drain: stores done before flag
    if (t == 0)
      __hip_atomic_store(&flb[q], s + 1, __ATOMIC_RELEASE,
                         __HIP_MEMORY_SCOPE_AGENT);
    if (t < 4 && t != q) {
      while (__hip_atomic_load(&flb[t], __ATOMIC_ACQUIRE,
                               __HIP_MEMORY_SCOPE_AGENT) < s + 1) {
      }
    }
    __syncthreads();
    if (t < 256) {
      float pre = uval + pown;
#pragma unroll
      for (int qq = 0; qq < 4; ++qq) {
        if (qq != q)
          pre += __hip_atomic_load(&Pg[par * 65536 + b * 1024 + qq * 256 + o],
                                   __ATOMIC_RELAXED, __HIP_MEMORY_SCOPE_AGENT);
      }
      float c = fast_tanh(pre);
      float gt = 1.f / (1.f + __expf((float)(3 * q) - dval));  // head q
      float hn = hloc[o];
      hn = gt * c + (1.f - gt) * hn;
      hloc[o] = hn;
      ach_h[o] = (f16)hn;
    }
    __syncthreads();
  }

  // ---- epilogue: fc1 partial over this WG's K-quarter (rows 256q..256q+256)
  {
    float acc = 0.f;
#pragma unroll 4
    for (int r = 0; r < 128; ++r) {
      int row = 256 * q + 128 * half + r;
      acc += hloc[128 * half + r] * fc1T[(size_t)row * 256 + o];
    }
    part[t] = acc;
  }
  __syncthreads();
  if (t < 256) FPg[b * 1024 + q * 256 + o] = part[o] + part[256 + o];
  __syncthreads();  // drain before flag
  if (t == 0)
    __hip_atomic_store(&flb[q], len + 1, __ATOMIC_RELEASE,
                       __HIP_MEMORY_SCOPE_AGENT);
  if (q != 0) return;
  if (t < 4 && t > 0) {
    while (__hip_atomic_load(&flb[t], __ATOMIC_ACQUIRE,
                             __HIP_MEMORY_SCOPE_AGENT) < len + 1) {
    }
  }
  __syncthreads();
  if (t < 256) {
    float pre = fc1_b[o];
#pragma unroll
    for (int qq = 0; qq < 4; ++qq)
      pre += __hip_atomic_load(&FPg[b * 1024 + qq * 256 + o], __ATOMIC_RELAXED,
                               __HIP_MEMORY_SCOPE_AGENT);
    hidb[o] = fast_tanh(pre);
  }
  __syncthreads();
  if (t < 64) {
    float p0 = 0.f, p1 = 0.f;
    for (int oi = t; oi < 256; oi += 64) {
      float h = hidb[oi];
      p0 += h * fc2_W[oi];
      p1 += h * fc2_W[256 + oi];
    }
#pragma unroll
    for (int off = 32; off; off >>= 1) {
      p0 += __shfl_down(p0, off);
      p1 += __shfl_down(p1, off);
    }
    if (t == 0) {
      out[b * 2 + 0] = p0 + fc2_b[0];
      out[b * 2 + 1] = p1 + fc2_b[1];
    }
  }
}

// ---------------------------------------------------------------------------
// Host launcher
// ws: [0,512K) Wpack | [512K,768K) WiT | [768K,1792K) fc1T | [1792K,18176K) U
//     | [18176K,18688K) Pg | [18688K,18944K) FPg | [18944K,+1K) Flg
// ---------------------------------------------------------------------------
extern "C" void kernel_launch(void* const* d_in, const int* in_sizes, int n_in,
                              void* d_out, int out_size, void* d_ws, size_t ws_size,
                              hipStream_t stream) {
  const int* src = (const int*)d_in[0];
  const int* input_len = (const int*)d_in[1];
  const float* fix_src = (const float*)d_in[2];
  const float* emb = (const float*)d_in[3];
  const float* Wi = (const float*)d_in[4];
  const float* bi = (const float*)d_in[5];
  const float* Wh = (const float*)d_in[6];
  const float* bh = (const float*)d_in[7];
  const float* fc1_W = (const float*)d_in[8];
  const float* fc1_b = (const float*)d_in[9];
  const float* fc2_W = (const float*)d_in[10];
  const float* fc2_b = (const float*)d_in[11];
  float* out = (float*)d_out;

  char* ws = (char*)d_ws;
  uint4* Wpack = (uint4*)(ws);                  // 512 KB
  float* WiT = (float*)(ws + (512ull << 10));   // 256 KB
  float* fc1T = (float*)(ws + (768ull << 10));  // 1 MB
  f16* U = (f16*)(ws + (1792ull << 10));        // 16 MB
  float* Pg = (float*)(ws + (18176ull << 10));  // 512 KB
  float* FPg = (float*)(ws + (18688ull << 10)); // 256 KB
  int* Flg = (int*)(ws + (18944ull << 10));     // 1 KB
  const size_t needed = (18945ull << 10);
  if (ws_size < needed) return;

  k_pack_wh<<<128, 256, 0, stream>>>(Wh, Wpack);
  k_transpose8<<<(65536 + 255) / 256, 256, 0, stream>>>(Wi, WiT, 256, 65536);
  k_transpose8<<<(262144 + 255) / 256, 256, 0, stream>>>(fc1_W, fc1T, 1024, 262144);
  k_precompute_u<<<BB * SS / 32, 256, 0, stream>>>(src, emb, WiT, bi, bh, U);
  k_init_flags<<<1, 256, 0, stream>>>(Flg);
  k_recurrence<<<BB * 4, TT, 0, stream>>>(Wpack, U, fix_src, input_len, fc1T,
                                          fc1_b, fc2_W, fc2_b, out, Pg, FPg, Flg);
}

// Round 7
// 973.671 us; speedup vs baseline: 2.4445x; 2.4445x over previous
//
#include <hip/hip_runtime.h>
#include <stdint.h>

// Problem constants
constexpr int BB = 64;     // batch
constexpr int SS = 512;    // seq len
constexpr int DD = 256;    // emb dim
constexpr int HH = 256;    // hidden
constexpr int NHH = 4;     // heads
constexpr int KK = 1024;   // NH*H recurrent input dim

// ALLOCATOR MODEL (consistent with rounds 2-6): VGPR budget/thread =
// 512 / (waves-per-SIMD implied by static-LDS occupancy):
//   60 KB LDS, 512 thr -> 2 WG/CU -> 4 w/SIMD -> 128 regs (r2-r4 observed)
//   63 KB LDS, 1024 thr -> 2 WG/CU -> 8 w/SIMD -> 64 regs (r5 observed)
//   4.6 KB LDS -> max occupancy -> <=64 regs (r6 observed)
// Attributes never moved it. THIS ROUND: static LDS = 95 KB > 80 KB ->
// only 1 WG/CU fits -> 2 waves/SIMD -> 256-reg budget. No asm pin (r5:
// pinning over budget = scratch catastrophe; r2: unpinned over-budget
// degrades gracefully by sinking only the excess).
//
// Geometry (r3): WG=512, one per batch. Thread t: g=t&63, ch=t>>6 covers
// outputs {g,g+64,g+128,g+192} x input chunk [128ch,128ch+128). 64 uint4
// slots/thread: slots 0-55 requested in VGPRs (224 regs), 56-63 in LDS.
constexpr int TT = 512;

typedef _Float16 f16;
typedef _Float16 f16x2 __attribute__((ext_vector_type(2)));

__device__ inline float dot2p(uint32_t a, uint32_t b, float c) {
  f16x2 av = __builtin_bit_cast(f16x2, a);
  f16x2 bv = __builtin_bit_cast(f16x2, b);
#if defined(__has_builtin)
#if __has_builtin(__builtin_amdgcn_fdot2)
  return __builtin_amdgcn_fdot2(av, bv, c, false);
#else
  return c + (float)av.x * (float)bv.x + (float)av.y * (float)bv.y;
#endif
#else
  return c + (float)av.x * (float)bv.x + (float)av.y * (float)bv.y;
#endif
}

__device__ inline float dot8(uint4 w, uint4 a, float c) {
  c = dot2p(w.x, a.x, c);
  c = dot2p(w.y, a.y, c);
  c = dot2p(w.z, a.z, c);
  c = dot2p(w.w, a.w, c);
  return c;
}

__device__ inline uint32_t pack2(float a, float b) {
  f16x2 v;
  v.x = (f16)a;
  v.y = (f16)b;
  return __builtin_bit_cast(uint32_t, v);
}

__device__ inline float fast_tanh(float x) {
  x = fminf(fmaxf(x, -15.f), 15.f);
  float e = __expf(2.f * x);
  return 1.f - 2.f / (e + 1.f);
}

// ---------------------------------------------------------------------------
// Prep A1: pack Wh [256,1024] fp32 -> Wpack f16, uniform slot layout:
// slot m (0..63): j = m>>2 (act-uint4 index), k = m&3 (output sel).
// Wpack[m*512 + t], t = ch*64 + g, holds Wh[g + 64k][128*ch + 8j .. +8).
// ---------------------------------------------------------------------------
__global__ void k_pack_wh(const float* __restrict__ Wh, uint4* __restrict__ Wpack) {
  int gid = blockIdx.x * blockDim.x + threadIdx.x;  // 32768
  int m = gid >> 9, t = gid & 511;
  int ch = t >> 6, g = t & 63;
  int j = m >> 2, k = m & 3;
  int row = g + 64 * k;
  int col = 128 * ch + 8 * j;
  const float* s = Wh + row * KK + col;
  uint4 w;
  w.x = pack2(s[0], s[1]);
  w.y = pack2(s[2], s[3]);
  w.z = pack2(s[4], s[5]);
  w.w = pack2(s[6], s[7]);
  Wpack[gid] = w;
}

// ---------------------------------------------------------------------------
// Prep A2/A3: transpose src[r, C] (r in [0,256)) -> dst[c*256 + r]
// ---------------------------------------------------------------------------
__global__ void k_transpose8(const float* __restrict__ src, float* __restrict__ dst,
                             int C, int total) {
  int gid = blockIdx.x * blockDim.x + threadIdx.x;
  if (gid >= total) return;
  int r = gid & 255, c = gid >> 8;
  dst[gid] = src[r * C + c];
}

// ---------------------------------------------------------------------------
// Prep B: U[row, o] = emb[src[row]] @ Wi^T + bi + bh   (f16 out)
// ---------------------------------------------------------------------------
__global__ __launch_bounds__(256) void k_precompute_u(
    const int* __restrict__ src, const float* __restrict__ emb,
    const float* __restrict__ WiT, const float* __restrict__ bi,
    const float* __restrict__ bh, f16* __restrict__ U) {
  __shared__ float xs[32 * 256];
  __shared__ int srcs[32];
  const int tid = threadIdx.x;
  const int row0 = blockIdx.x * 32;
  if (tid < 32) srcs[tid] = src[row0 + tid];
  __syncthreads();
  for (int i = tid; i < 32 * 256; i += 256) {
    int r = i >> 8, d = i & 255;
    xs[i] = emb[srcs[r] * DD + d];
  }
  __syncthreads();
  const int o = tid;
  float acc[32];
#pragma unroll
  for (int r = 0; r < 32; ++r) acc[r] = 0.f;
  for (int d0 = 0; d0 < 256; d0 += 8) {
    float w[8];
#pragma unroll
    for (int j = 0; j < 8; ++j) w[j] = WiT[(d0 + j) * 256 + o];  // coalesced
#pragma unroll
    for (int r = 0; r < 32; ++r) {
      const float4* xp = (const float4*)(xs + r * 256 + d0);  // broadcast
      float4 x0 = xp[0], x1 = xp[1];
      acc[r] += x0.x * w[0] + x0.y * w[1] + x0.z * w[2] + x0.w * w[3] +
                x1.x * w[4] + x1.y * w[5] + x1.z * w[6] + x1.w * w[7];
    }
  }
  float bias = bi[o] + bh[o];
#pragma unroll
  for (int r = 0; r < 32; ++r)
    U[(size_t)(row0 + r) * HH + o] = (f16)(acc[r] + bias);
}

// ---------------------------------------------------------------------------
// Main recurrence: one WG (512 threads = 8 waves) per batch element.
// 95 KB static LDS -> 1 WG/CU -> 2 waves/SIMD -> 256-VGPR budget.
// ---------------------------------------------------------------------------
__global__ void __attribute__((amdgpu_flat_work_group_size(512, 512),
                               amdgpu_waves_per_eu(2, 2)))
k_recurrence(
    const uint4* __restrict__ Wpack, const f16* __restrict__ U,
    const float* __restrict__ fix_src, const int* __restrict__ input_len,
    const float* __restrict__ fc1T, const float* __restrict__ fc1_b,
    const float* __restrict__ fc2_W, const float* __restrict__ fc2_b,
    float* __restrict__ out) {
  // 95 KB static LDS total: occupancy-1 is the POINT (raises reg budget).
  __shared__ uint4 wlds[10 * TT];     // 80 KB; slots 56-63 in [0,8); 16 KB tail unused
  __shared__ uint4 hcatv[KK / 8];     // 2 KB f16 activations
  __shared__ float hstate[NHH * HH];  // 4 KB fp32 master h
  __shared__ float partials[2048];    // 8 KB
  __shared__ float hidb[HH];          // 1 KB
  f16* hcat_h = (f16*)hcatv;

  const int b = blockIdx.x;
  const int t = threadIdx.x;
  const int o = t & 255;
  const int g = t & 63, ch = t >> 6;

  // one-time: weights into VGPRs (56 slots requested; allocator keeps what
  // fits the 256 budget, sinks only the excess) + LDS (8 slots)
  uint4 wv[56];
#pragma unroll
  for (int m = 0; m < 56; ++m) wv[m] = Wpack[m * TT + t];
#pragma unroll
  for (int i = 0; i < 8; ++i) wlds[i * TT + t] = Wpack[(56 + i) * TT + t];
  hstate[t] = 0.f;
  hstate[512 + t] = 0.f;
  if (t < KK / 8) hcatv[t] = make_uint4(0u, 0u, 0u, 0u);
  __syncthreads();

  const int len = input_len[b];
  const f16* Ub = U + (size_t)b * SS * HH;
  const float* fsb = fix_src + b * SS;
  const uint4* actp = hcatv + ch * 16;  // wave-uniform base -> broadcast reads

#pragma unroll 1
  for (int step = 0; step < len; ++step) {
    float uval = 0.f, dval = 0.f;
    if (t < 256) {
      uval = (float)Ub[step * HH + o];
      dval = fsb[step];
    }
    float a0 = 0.f, a1 = 0.f, a2 = 0.f, a3 = 0.f;
#pragma unroll
    for (int j = 0; j < 14; ++j) {  // VGPR-resident region (slots 0..55)
      uint4 a = actp[j];
      a0 = dot8(wv[4 * j + 0], a, a0);
      a1 = dot8(wv[4 * j + 1], a, a1);
      a2 = dot8(wv[4 * j + 2], a, a2);
      a3 = dot8(wv[4 * j + 3], a, a3);
    }
#pragma unroll
    for (int j = 14; j < 16; ++j) {  // LDS region (slots 56..63)
      uint4 a = actp[j];
      int i4 = 4 * (j - 14);
      a0 = dot8(wlds[(i4 + 0) * TT + t], a, a0);
      a1 = dot8(wlds[(i4 + 1) * TT + t], a, a1);
      a2 = dot8(wlds[(i4 + 2) * TT + t], a, a2);
      a3 = dot8(wlds[(i4 + 3) * TT + t], a, a3);
    }
    partials[ch * 256 + g] = a0;
    partials[ch * 256 + 64 + g] = a1;
    partials[ch * 256 + 128 + g] = a2;
    partials[ch * 256 + 192 + g] = a3;
    __syncthreads();
    if (t < 256) {
      float pre = uval;
#pragma unroll
      for (int c2 = 0; c2 < 8; ++c2) pre += partials[c2 * 256 + o];
      float c = fast_tanh(pre);
#pragma unroll
      for (int n = 0; n < NHH; ++n) {
        float gt = 1.f / (1.f + __expf((float)(3 * n) - dval));
        float hn = hstate[n * HH + o];
        hn = gt * c + (1.f - gt) * hn;
        hstate[n * HH + o] = hn;
        hcat_h[n * HH + o] = (f16)hn;
      }
    }
    __syncthreads();
  }

  // ---- epilogue: hid = tanh(sel @ fc1_W^T + fc1_b); out = hid @ fc2_W^T + fc2_b
  {
    float acc = 0.f;
    const int q2 = t >> 8;  // 0..1
    const int base = q2 * 512;
    for (int i = 0; i < 512; ++i) {
      acc += hstate[base + i] * fc1T[(size_t)(base + i) * HH + o];
    }
    partials[q2 * 256 + o] = acc;
  }
  __syncthreads();
  if (t < 256) {
    float pre = partials[o] + partials[256 + o] + fc1_b[o];
    hidb[o] = fast_tanh(pre);
  }
  __syncthreads();
  if (t < 64) {
    float p0 = 0.f, p1 = 0.f;
    for (int oi = t; oi < 256; oi += 64) {
      float h = hidb[oi];
      p0 += h * fc2_W[oi];
      p1 += h * fc2_W[256 + oi];
    }
#pragma unroll
    for (int off = 32; off; off >>= 1) {
      p0 += __shfl_down(p0, off);
      p1 += __shfl_down(p1, off);
    }
    if (t == 0) {
      out[b * 2 + 0] = p0 + fc2_b[0];
      out[b * 2 + 1] = p1 + fc2_b[1];
    }
  }
}

// ---------------------------------------------------------------------------
// Host launcher
// ws layout: [0,512K) Wpack | [512K,768K) WiT | [768K,1792K) fc1T | [1792K,+16M) U
// ---------------------------------------------------------------------------
extern "C" void kernel_launch(void* const* d_in, const int* in_sizes, int n_in,
                              void* d_out, int out_size, void* d_ws, size_t ws_size,
                              hipStream_t stream) {
  const int* src = (const int*)d_in[0];
  const int* input_len = (const int*)d_in[1];
  const float* fix_src = (const float*)d_in[2];
  const float* emb = (const float*)d_in[3];
  const float* Wi = (const float*)d_in[4];
  const float* bi = (const float*)d_in[5];
  const float* Wh = (const float*)d_in[6];
  const float* bh = (const float*)d_in[7];
  const float* fc1_W = (const float*)d_in[8];
  const float* fc1_b = (const float*)d_in[9];
  const float* fc2_W = (const float*)d_in[10];
  const float* fc2_b = (const float*)d_in[11];
  float* out = (float*)d_out;

  char* ws = (char*)d_ws;
  uint4* Wpack = (uint4*)(ws);                 // 512 KB
  float* WiT = (float*)(ws + (512ull << 10));  // 256 KB
  float* fc1T = (float*)(ws + (768ull << 10)); // 1 MB
  f16* U = (f16*)(ws + (1792ull << 10));       // 16 MB
  const size_t needed = (1792ull << 10) + (size_t)BB * SS * HH * sizeof(f16);
  if (ws_size < needed) return;

  k_pack_wh<<<128, 256, 0, stream>>>(Wh, Wpack);
  k_transpose8<<<(65536 + 255) / 256, 256, 0, stream>>>(Wi, WiT, 256, 65536);
  k_transpose8<<<(262144 + 255) / 256, 256, 0, stream>>>(fc1_W, fc1T, 1024, 262144);
  k_precompute_u<<<BB * SS / 32, 256, 0, stream>>>(src, emb, WiT, bi, bh, U);
  k_recurrence<<<BB, TT, 0, stream>>>(Wpack, U, fix_src, input_len, fc1T, fc1_b,
                                      fc2_W, fc2_b, out);
}

// Round 10
// 897.625 us; speedup vs baseline: 2.6516x; 1.0847x over previous
//
#include <hip/hip_runtime.h>
#include <stdint.h>

// Problem constants
constexpr int BB = 64;     // batch
constexpr int SS = 512;    // seq len
constexpr int DD = 256;    // emb dim
constexpr int HH = 256;    // hidden
constexpr int NHH = 4;     // heads
constexpr int KK = 1024;   // NH*H recurrent input dim

// HARD FACTS (r2-r9): VGPR budget = 128 iff static LDS forces <=2 WG/CU,
// else 64; never more (launch_bounds/waves_per_eu/AGPR all failed). Step
// time == streamed_weight_bytes / 64 B/cyc (r7). Release/acquire cross-CU
// sync ~4us/step -- the fences, not the payload (r6). fp8/int8 weights
// break accuracy (r8).
//
// ROUND 10: algebraic restructure. g_n(t) is SCALAR per (b,head,step), so
// with v_n := h_n @ Wh_n^T:  v_n(t) = g_n * (c(t) @ Wh_n^T) + (1-g_n) v_n(t-1),
// pre(t) = U(t) + sum_n v_n(t-1). Matvec input is c (256-dim) -> split the
// 256 c-columns over 4 CUs: each CU owns 256 outputs (4 heads x 64 cols) x
// 256 inputs = 128 KB = 16 uint4/thread = 64 VGPRs. Fully resident under
// the 128 budget. Per-step exchange = 64 c-values/CU, published as
// self-tagged dwords ((f16 c)<<16 | step tag) with RELAXED device-scope
// atomics -- no fences at all. Parity double-buffer (r6-proven race-free:
// observing a peer's tag s+2 proves it finished reading tag s+1).
constexpr int TT = 512;

typedef _Float16 f16;
typedef _Float16 f16x2 __attribute__((ext_vector_type(2)));

__device__ inline float dot2p(uint32_t a, uint32_t b, float c) {
  f16x2 av = __builtin_bit_cast(f16x2, a);
  f16x2 bv = __builtin_bit_cast(f16x2, b);
#if defined(__has_builtin)
#if __has_builtin(__builtin_amdgcn_fdot2)
  return __builtin_amdgcn_fdot2(av, bv, c, false);
#else
  return c + (float)av.x * (float)bv.x + (float)av.y * (float)bv.y;
#endif
#else
  return c + (float)av.x * (float)bv.x + (float)av.y * (float)bv.y;
#endif
}

__device__ inline float dot8(uint4 w, uint4 a, float c) {
  c = dot2p(w.x, a.x, c);
  c = dot2p(w.y, a.y, c);
  c = dot2p(w.z, a.z, c);
  c = dot2p(w.w, a.w, c);
  return c;
}

__device__ inline uint32_t pack2(float a, float b) {
  f16x2 v;
  v.x = (f16)a;
  v.y = (f16)b;
  return __builtin_bit_cast(uint32_t, v);
}

__device__ inline float fast_tanh(float x) {
  x = fminf(fmaxf(x, -15.f), 15.f);
  float e = __expf(2.f * x);
  return 1.f - 2.f / (e + 1.f);
}

// ---------------------------------------------------------------------------
// Prep A1: pack Wh [256,1024] fp32 -> Wq f16 for the v-form matvec.
// Wq[(p*16 + m)*512 + t]: t -> out=t&255 (n=out>>6, o_loc=out&63), ch2=t>>8.
// Holds Wh[64p + o_loc][256n + 128*ch2 + 8m .. +8) as 8 packed f16.
// ---------------------------------------------------------------------------
__global__ void k_pack_wq(const float* __restrict__ Wh, uint4* __restrict__ Wq) {
  int gid = blockIdx.x * blockDim.x + threadIdx.x;  // 32768
  int p = gid >> 13;
  int m = (gid >> 9) & 15;
  int t = gid & 511;
  int out = t & 255, ch2 = t >> 8;
  int n = out >> 6, o_loc = out & 63;
  const float* s = Wh + (64 * p + o_loc) * KK + 256 * n + 128 * ch2 + 8 * m;
  uint4 w;
  w.x = pack2(s[0], s[1]);
  w.y = pack2(s[2], s[3]);
  w.z = pack2(s[4], s[5]);
  w.w = pack2(s[6], s[7]);
  Wq[gid] = w;
}

// ---------------------------------------------------------------------------
// Prep A2/A3: transpose src[r, C] (r in [0,256)) -> dst[c*256 + r]
// ---------------------------------------------------------------------------
__global__ void k_transpose8(const float* __restrict__ src, float* __restrict__ dst,
                             int C, int total) {
  int gid = blockIdx.x * blockDim.x + threadIdx.x;
  if (gid >= total) return;
  int r = gid & 255, c = gid >> 8;
  dst[gid] = src[r * C + c];
}

// ---------------------------------------------------------------------------
// Prep B: U[row, o] = emb[src[row]] @ Wi^T + bi + bh (f16). Blocks beyond
// input_len[b] skipped.
// ---------------------------------------------------------------------------
__global__ __launch_bounds__(256) void k_precompute_u(
    const int* __restrict__ src, const float* __restrict__ emb,
    const float* __restrict__ WiT, const float* __restrict__ bi,
    const float* __restrict__ bh, const int* __restrict__ input_len,
    f16* __restrict__ U) {
  const int row0 = blockIdx.x * 32;
  const int b = row0 >> 9;
  if ((row0 & 511) >= input_len[b]) return;
  __shared__ float xs[32 * 256];
  __shared__ int srcs[32];
  const int tid = threadIdx.x;
  if (tid < 32) srcs[tid] = src[row0 + tid];
  __syncthreads();
  for (int i = tid; i < 32 * 256; i += 256) {
    int r = i >> 8, d = i & 255;
    xs[i] = emb[srcs[r] * DD + d];
  }
  __syncthreads();
  const int o = tid;
  float acc[32];
#pragma unroll
  for (int r = 0; r < 32; ++r) acc[r] = 0.f;
  for (int d0 = 0; d0 < 256; d0 += 8) {
    float w[8];
#pragma unroll
    for (int j = 0; j < 8; ++j) w[j] = WiT[(d0 + j) * 256 + o];  // coalesced
#pragma unroll
    for (int r = 0; r < 32; ++r) {
      const float4* xp = (const float4*)(xs + r * 256 + d0);  // broadcast
      float4 x0 = xp[0], x1 = xp[1];
      acc[r] += x0.x * w[0] + x0.y * w[1] + x0.z * w[2] + x0.w * w[3] +
                x1.x * w[4] + x1.y * w[5] + x1.z * w[6] + x1.w * w[7];
    }
  }
  float bias = bi[o] + bh[o];
#pragma unroll
  for (int r = 0; r < 32; ++r)
    U[(size_t)(row0 + r) * HH + o] = (f16)(acc[r] + bias);
}

// ---------------------------------------------------------------------------
// Main recurrence (v-form): 4 WGs (512 thr) per batch, blockIdx = p*64 + b
// (same-XCD heuristic; correctness is placement-independent). Thread t:
// out = t&255 (n=out>>6, o_loc=out&63), ch2 = t>>8 (input half).
// 16 resident uint4 weights/thread. 60 KB LDS arena pins the 2-WG/CU
// occupancy class -> 128-reg budget; 256 WGs always co-resident (cap 512).
// ---------------------------------------------------------------------------
__global__ void __attribute__((amdgpu_flat_work_group_size(512, 512)))
k_recurrence(
    const uint4* __restrict__ Wq, const f16* __restrict__ U,
    const float* __restrict__ fix_src, const int* __restrict__ input_len,
    const float* __restrict__ fc1T, const float* __restrict__ fc1_b,
    const float* __restrict__ fc2_W, const float* __restrict__ fc2_b,
    float* __restrict__ out, uint32_t* __restrict__ Cex,
    float* __restrict__ FPg, int* __restrict__ Flg) {
  __shared__ __align__(16) char arena[61440];  // 60 KB -> 2 WG/CU class
  f16* cbuf = (f16*)arena;                    // [0,512): c as f16[256]
  uint4* cvec = (uint4*)arena;                // same bytes, 32 uint4
  float* partials = (float*)(arena + 512);    // [512,2560): 512 floats
  float* vbuf = (float*)(arena + 2560);       // [2560,3584): 256 floats
  float* zbuf = (float*)(arena + 3584);       // [3584,3840): 64 floats
  float* hbuf = (float*)(arena + 3840);       // [3840,4864): 256 floats

  const int idx = blockIdx.x;
  const int b = idx & 63;
  const int p = idx >> 6;
  const int t = threadIdx.x;
  const int out_i = t & 255, ch2 = t >> 8;
  const int n = out_i >> 6, o_loc = out_i & 63;

  // one-time: this CU's 128 KB weight slab into VGPRs (64 regs)
  uint4 w[16];
  const uint4* wp = Wq + (p * 16) * TT + t;
#pragma unroll
  for (int m = 0; m < 16; ++m) w[m] = wp[m * TT];
#pragma unroll
  for (int m = 0; m < 16; ++m)
    asm volatile("" : "+v"(w[m].x), "+v"(w[m].y), "+v"(w[m].z), "+v"(w[m].w));

  if (t < 64) zbuf[t] = 0.f;
  float v = 0.f;  // v_n[o] for out_i (threads t<256)
  float h = 0.f;  // h_n[64p + o_loc]   (threads t<256)
  __syncthreads();

  const int len = input_len[b];
  const f16* Ub = U + (size_t)b * SS * HH;
  const float* fsb = fix_src + b * SS;

#pragma unroll 1
  for (int s = 0; s < len; ++s) {
    const int par = s & 1;
    const uint32_t tag = (uint32_t)((s + 1) & 0xffff);
    float dval = fsb[s];
    if (t < 64) {
      // c for own 64 columns; publish self-tagged (relaxed, fence-free)
      float uval = (float)Ub[(size_t)s * HH + 64 * p + t];
      float c = fast_tanh(uval + zbuf[t]);
      f16 chv = (f16)c;
      cbuf[64 * p + t] = chv;
      uint32_t dw =
          ((uint32_t)__builtin_bit_cast(unsigned short, chv) << 16) | tag;
      __hip_atomic_store(&Cex[((par * 64 + b) * 4 + p) * 64 + t], dw,
                         __ATOMIC_RELAXED, __HIP_MEMORY_SCOPE_AGENT);
    } else if (t < 256) {
      // waves 1..3: each gathers one peer's 64 self-tagged dwords
      int wv = t >> 6;              // 1,2,3
      int lane = t & 63;
      int q = (p + wv) & 3;         // peer CU
      uint32_t* addr = &Cex[((par * 64 + b) * 4 + q) * 64 + lane];
      uint32_t dw;
      do {
        dw = __hip_atomic_load(addr, __ATOMIC_RELAXED,
                               __HIP_MEMORY_SCOPE_AGENT);
      } while ((dw & 0xffffu) != tag);
      cbuf[64 * q + lane] =
          __builtin_bit_cast(f16, (unsigned short)(dw >> 16));
    }
    __syncthreads();  // B1: full c in cbuf

    // matvec: w_out = sum_i c[256n + ...]: thread covers out_i x 128 inputs
    float acc = 0.f;
    const uint4* ap = cvec + ch2 * 16;  // wave-uniform -> broadcast
#pragma unroll
    for (int m = 0; m < 16; ++m) acc = dot8(w[m], ap[m], acc);
    partials[t] = acc;  // t = ch2*256 + out_i
    __syncthreads();    // B2

    if (t < 256) {
      float wsum = partials[out_i] + partials[256 + out_i];
      float g = 1.f / (1.f + __expf((float)(3 * n) - dval));
      v = g * wsum + (1.f - g) * v;
      vbuf[out_i] = v;
      float cown = (float)cbuf[64 * p + o_loc];
      h = g * cown + (1.f - g) * h;
    }
    __syncthreads();  // B3
    if (t < 64)
      zbuf[t] = vbuf[t] + vbuf[64 + t] + vbuf[128 + t] + vbuf[192 + t];
    // zbuf written+read by wave 0 only -> intra-wave ordering suffices
  }

  // ---- epilogue: fc1 partial over this CU's 256 k's, then one-time sync
  if (t < 256) hbuf[out_i] = h;  // hbuf[k_loc]: n=k_loc>>6, i=64p+(k_loc&63)
  __syncthreads();
  {
    float acc = 0.f;
#pragma unroll 4
    for (int r = 0; r < 128; ++r) {
      int k_loc = ch2 * 128 + r;
      int n2 = k_loc >> 6, il = k_loc & 63;
      int kg = n2 * 256 + 64 * p + il;
      acc += hbuf[k_loc] * fc1T[(size_t)kg * 256 + out_i];
    }
    partials[t] = acc;
  }
  __syncthreads();
  if (t < 256) FPg[(b * 4 + p) * 256 + out_i] =
      partials[out_i] + partials[256 + out_i];
  __syncthreads();  // barrier drains stores before flag
  if (t == 0)
    __hip_atomic_store(&Flg[b * 4 + p], 0x5A5A5A5A, __ATOMIC_RELEASE,
                       __HIP_MEMORY_SCOPE_AGENT);
  if (p != 0) return;
  if (t < 4 && t > 0) {
    while (__hip_atomic_load(&Flg[b * 4 + t], __ATOMIC_ACQUIRE,
                             __HIP_MEMORY_SCOPE_AGENT) != 0x5A5A5A5A) {
    }
  }
  __syncthreads();
  if (t < 256) {
    float pre = fc1_b[t];
#pragma unroll
    for (int q = 0; q < 4; ++q)
      pre += __hip_atomic_load(&FPg[(b * 4 + q) * 256 + t], __ATOMIC_RELAXED,
                               __HIP_MEMORY_SCOPE_AGENT);
    hbuf[t] = fast_tanh(pre);  // reuse as hid
  }
  __syncthreads();
  if (t < 64) {
    float p0 = 0.f, p1 = 0.f;
    for (int oi = t; oi < 256; oi += 64) {
      float hh = hbuf[oi];
      p0 += hh * fc2_W[oi];
      p1 += hh * fc2_W[256 + oi];
    }
#pragma unroll
    for (int off = 32; off; off >>= 1) {
      p0 += __shfl_down(p0, off);
      p1 += __shfl_down(p1, off);
    }
    if (t == 0) {
      out[b * 2 + 0] = p0 + fc2_b[0];
      out[b * 2 + 1] = p1 + fc2_b[1];
    }
  }
}

// ---------------------------------------------------------------------------
// Host launcher
// ws: [0,512K) Wq | [512K,768K) WiT | [768K,1792K) fc1T | [1792K,18176K) U
//     | [18176K,18304K) Cex | [18304K,18560K) FPg | [18560K,+1K) Flg
// Cex/Flg need no init: 0xAA poison never matches a tag (0xAAAA>512) or the
// 0x5A5A5A5A magic.
// ---------------------------------------------------------------------------
extern "C" void kernel_launch(void* const* d_in, const int* in_sizes, int n_in,
                              void* d_out, int out_size, void* d_ws, size_t ws_size,
                              hipStream_t stream) {
  const int* src = (const int*)d_in[0];
  const int* input_len = (const int*)d_in[1];
  const float* fix_src = (const float*)d_in[2];
  const float* emb = (const float*)d_in[3];
  const float* Wi = (const float*)d_in[4];
  const float* bi = (const float*)d_in[5];
  const float* Wh = (const float*)d_in[6];
  const float* bh = (const float*)d_in[7];
  const float* fc1_W = (const float*)d_in[8];
  const float* fc1_b = (const float*)d_in[9];
  const float* fc2_W = (const float*)d_in[10];
  const float* fc2_b = (const float*)d_in[11];
  float* out = (float*)d_out;

  char* ws = (char*)d_ws;
  uint4* Wq = (uint4*)(ws);                          // 512 KB
  float* WiT = (float*)(ws + (512ull << 10));        // 256 KB
  float* fc1T = (float*)(ws + (768ull << 10));       // 1 MB
  f16* U = (f16*)(ws + (1792ull << 10));             // 16 MB
  uint32_t* Cex = (uint32_t*)(ws + (18176ull << 10)); // 128 KB
  float* FPg = (float*)(ws + (18304ull << 10));      // 256 KB
  int* Flg = (int*)(ws + (18560ull << 10));          // 1 KB
  const size_t needed = (18561ull << 10);
  if (ws_size < needed) return;

  k_pack_wq<<<128, 256, 0, stream>>>(Wh, Wq);
  k_transpose8<<<(65536 + 255) / 256, 256, 0, stream>>>(Wi, WiT, 256, 65536);
  k_transpose8<<<(262144 + 255) / 256, 256, 0, stream>>>(fc1_W, fc1T, 1024, 262144);
  k_precompute_u<<<BB * SS / 32, 256, 0, stream>>>(src, emb, WiT, bi, bh,
                                                   input_len, U);
  k_recurrence<<<BB * 4, TT, 0, stream>>>(Wq, U, fix_src, input_len, fc1T,
                                          fc1_b, fc2_W, fc2_b, out, Cex, FPg,
                                          Flg);
}